// Round 2
// baseline (169.320 us; speedup 1.0000x reference)
//
#include <hip/hip_runtime.h>

#define BDIM 128
#define TDIM 512
#define DDIM 64
#define HDIM 256
#define TCHUNK 128   // timesteps per wave-group (4 groups)

typedef short s16x8 __attribute__((ext_vector_type(8)));
typedef float f32x4 __attribute__((ext_vector_type(4)));

__device__ __forceinline__ short f2bf(float f) {
  __bf16 b = (__bf16)f;
  return __builtin_bit_cast(short, b);
}

__device__ __forceinline__ s16x8 pack_bf8(float4 lo, float4 hi) {
  s16x8 v;
  v[0] = f2bf(lo.x); v[1] = f2bf(lo.y); v[2] = f2bf(lo.z); v[3] = f2bf(lo.w);
  v[4] = f2bf(hi.x); v[5] = f2bf(hi.y); v[6] = f2bf(hi.z); v[7] = f2bf(hi.w);
  return v;
}

__device__ __forceinline__ float rcpf(float x) { return __builtin_amdgcn_rcpf(x); }
__device__ __forceinline__ float sigm(float x) { return rcpf(1.0f + __expf(-x)); }
__device__ __forceinline__ float tanh_fast(float x) { return 1.0f - 2.0f * rcpf(__expf(2.0f * x) + 1.0f); }

// Grid: (128, 4) blocks, 1024 threads (16 waves). Block = (b, h-chunk of 64).
// wave = tg*4 + hslice: hslice picks 16 h-cols, tg picks a 128-timestep range.
__global__ __launch_bounds__(1024, 8) void fused_lstm(
    const float* __restrict__ x, const float* __restrict__ h0,
    const float* __restrict__ c0, const float* __restrict__ Wih,
    const float* __restrict__ Whh, const float* __restrict__ bih,
    const float* __restrict__ bhh, const int* __restrict__ longp,
    float* __restrict__ sbuf)
{
  const int b    = blockIdx.x;
  const int hc   = blockIdx.y;          // 0..3
  const int tid  = threadIdx.x;
  const int wave = tid >> 6;            // 0..15
  const int lane = tid & 63;
  const int col  = lane & 15;
  const int kg   = lane >> 4;           // 0..3
  const int hslice = wave & 3;          // 0..3
  const int tg     = wave >> 2;         // 0..3
  const int h    = hc * 64 + hslice * 16 + col;

  __shared__ float hs[HDIM];
  __shared__ float w0s[TDIM];
  __shared__ float w1s[TDIM];
  __shared__ float hh_s[256];           // [g*64 + h_local]
  __shared__ float red[4 * 256];        // [tg][hslice][q][col]

  const float* xb = x + (size_t)b * (TDIM * DDIM);
  const float inv_long = 1.0f / (float)(*longp);

  if (tid < HDIM) hs[tid] = h0[b * HDIM + tid];
  if (tid < TDIM) {
    // zero t=0 so the mask needs no branch in the hot loop
    w0s[tid] = (tid == 0) ? 0.f : xb[tid * DDIM + 0] * inv_long;
    w1s[tid] = (tid == 0) ? 0.f : xb[tid * DDIM + 1];
  }
  __syncthreads();

  // hh term: 256 gate-cols, 4 threads each (64 MACs per thread), fp32
  {
    const int g    = tid >> 8;          // 0..3
    const int hl   = (tid >> 2) & 63;
    const int part = tid & 3;
    const int colw = g * HDIM + hc * 64 + hl;
    const float4* wr = (const float4*)(Whh + (size_t)colw * HDIM) + part * 16;
    const float4* hv = (const float4*)hs + part * 16;
    float acc = 0.f;
    #pragma unroll 8
    for (int k = 0; k < 16; ++k) {
      float4 w = wr[k], h4 = hv[k];
      acc += w.x * h4.x + w.y * h4.y + w.z * h4.z + w.w * h4.w;
    }
    acc += __shfl_xor(acc, 1, 64);
    acc += __shfl_xor(acc, 2, 64);
    if (part == 0) hh_s[g * 64 + hl] = acc + bih[colw] + bhh[colw];
  }
  __syncthreads();

  float hhv[4];
  #pragma unroll
  for (int g = 0; g < 4; ++g) hhv[g] = hh_s[g * 64 + hslice * 16 + col];
  const float cprev = c0[b * HDIM + h];

  // W_ih fragments: B[k][n] = W_ih[n][k]; contiguous 8-float read per lane.
  s16x8 wf[4][2];
  #pragma unroll
  for (int g = 0; g < 4; ++g) {
    const float4* wrow = (const float4*)(Wih + (size_t)(g * HDIM + h) * DDIM);
    #pragma unroll
    for (int ks = 0; ks < 2; ++ks)
      wf[g][ks] = pack_bf8(wrow[kg * 2 + ks * 8], wrow[kg * 2 + ks * 8 + 1]);
  }

  float s0h = 0.f, s1h = 0.f, s0c = 0.f, s1c = 0.f;

  // A fragment: row = t0 + tb + (lane&15), k = kg*8 + j (+32)
  const int t0 = tg * TCHUNK;
  const float* arow = xb + (size_t)(t0 + col) * DDIM + kg * 8;

  float4 cur0 = *(const float4*)(arow + 0);
  float4 cur1 = *(const float4*)(arow + 4);
  float4 cur2 = *(const float4*)(arow + 32);
  float4 cur3 = *(const float4*)(arow + 36);
  float4 nxt0 = cur0, nxt1 = cur1, nxt2 = cur2, nxt3 = cur3;

  for (int tb = 0; tb < TCHUNK; tb += 16) {
    if (tb + 16 < TCHUNK) {
      const float* p = arow + (size_t)(tb + 16) * DDIM;
      nxt0 = *(const float4*)(p + 0);
      nxt1 = *(const float4*)(p + 4);
      nxt2 = *(const float4*)(p + 32);
      nxt3 = *(const float4*)(p + 36);
    }
    s16x8 a0 = pack_bf8(cur0, cur1);
    s16x8 a1 = pack_bf8(cur2, cur3);

    f32x4 acc[4];
    #pragma unroll
    for (int g = 0; g < 4; ++g) {
      f32x4 z = {hhv[g], hhv[g], hhv[g], hhv[g]};   // bias+hh folded into C
      z = __builtin_amdgcn_mfma_f32_16x16x32_bf16(a0, wf[g][0], z, 0, 0, 0);
      z = __builtin_amdgcn_mfma_f32_16x16x32_bf16(a1, wf[g][1], z, 0, 0, 0);
      acc[g] = z;
    }

    #pragma unroll
    for (int r = 0; r < 4; ++r) {
      const int tt = t0 + tb + kg * 4 + r;   // C/D row = kg*4+r, col = lane&15
      float ig = sigm(acc[0][r]);
      float fg = sigm(acc[1][r]);
      float gg = tanh_fast(acc[2][r]);
      float og = sigm(acc[3][r]);
      float cc = fg * cprev + ig * gg;
      float hv = og * tanh_fast(cc);
      float a0w = w0s[tt], a1w = w1s[tt];    // w*[0]==0 handles the t=0 mask
      s0h += hv * a0w; s1h += hv * a1w;
      s0c += cc * a0w; s1c += cc * a1w;
    }
    cur0 = nxt0; cur1 = nxt1; cur2 = nxt2; cur3 = nxt3;
  }

  // reduce over the 4 k-groups (lanes sharing col)
  s0h += __shfl_xor(s0h, 16, 64); s0h += __shfl_xor(s0h, 32, 64);
  s1h += __shfl_xor(s1h, 16, 64); s1h += __shfl_xor(s1h, 32, 64);
  s0c += __shfl_xor(s0c, 16, 64); s0c += __shfl_xor(s0c, 32, 64);
  s1c += __shfl_xor(s1c, 16, 64); s1c += __shfl_xor(s1c, 32, 64);

  if (kg == 0) {
    const int base = tg * 256 + hslice * 64 + col;
    red[base +  0] = s0h;
    red[base + 16] = s1h;
    red[base + 32] = s0c;
    red[base + 48] = s1c;
  }
  __syncthreads();

  // combine the 4 t-groups; 256 threads write sbuf
  if (tid < 256) {
    const int hs2  = tid >> 6;
    const int q    = (tid >> 4) & 3;
    const int col2 = tid & 15;
    const int off  = hs2 * 64 + q * 16 + col2;
    float s = red[off] + red[256 + off] + red[512 + off] + red[768 + off];
    const int h2 = hc * 64 + hs2 * 16 + col2;
    sbuf[q * (BDIM * HDIM) + b * HDIM + h2] = s;
  }
}

// Grid: 128 blocks (b), 256 threads. Epilogue GEMV + bias*Wsum terms.
__global__ __launch_bounds__(256) void out_kernel(
    const float* __restrict__ x, const float* __restrict__ f1w,
    const float* __restrict__ f1b, const float* __restrict__ f2w,
    const float* __restrict__ f2b, const int* __restrict__ longp,
    const float* __restrict__ sbuf, float* __restrict__ out)
{
  const int b = blockIdx.x, tid = threadIdx.x;
  __shared__ float s0h[256], s1h[256], s0c[256], s1c[256];
  __shared__ float wsum[8];
  const float* xb = x + (size_t)b * (TDIM * DDIM);

  s0h[tid] = sbuf[0 * (BDIM * HDIM) + b * HDIM + tid];
  s1h[tid] = sbuf[1 * (BDIM * HDIM) + b * HDIM + tid];
  s0c[tid] = sbuf[2 * (BDIM * HDIM) + b * HDIM + tid];
  s1c[tid] = sbuf[3 * (BDIM * HDIM) + b * HDIM + tid];

  float w0p = 0.f, w1p = 0.f;
  for (int t = tid; t < TDIM; t += 256) {
    w0p += xb[t * DDIM];
    w1p += xb[t * DDIM + 1];
  }
  #pragma unroll
  for (int off = 1; off < 64; off <<= 1) {
    w0p += __shfl_xor(w0p, off, 64);
    w1p += __shfl_xor(w1p, off, 64);
  }
  if ((tid & 63) == 0) { wsum[tid >> 6] = w0p; wsum[4 + (tid >> 6)] = w1p; }
  __syncthreads();

  const float inv_long = 1.0f / (float)(*longp);
  const float W0 = (wsum[0] + wsum[1] + wsum[2] + wsum[3]) * inv_long; // all t
  const float W1 = (wsum[4] + wsum[5] + wsum[6] + wsum[7]);

  float rh, rc;
  if (tid < 128) {                       // "first": f1_w with w0-weighted sums
    const float4* wr = (const float4*)(f1w + (size_t)tid * HDIM);
    float ah = 0.f, ac = 0.f;
    #pragma unroll 8
    for (int k = 0; k < HDIM / 4; ++k) {
      float4 w = wr[k];
      ah += w.x * s0h[4*k] + w.y * s0h[4*k+1] + w.z * s0h[4*k+2] + w.w * s0h[4*k+3];
      ac += w.x * s0c[4*k] + w.y * s0c[4*k+1] + w.z * s0c[4*k+2] + w.w * s0c[4*k+3];
    }
    const float bb = f1b[tid];
    rh = ah + bb * W0;
    rc = ac + bb * W0;
  } else {                               // "second": f2_w with w1-weighted sums
    const int k0 = tid - 128;
    const float4* wr = (const float4*)(f2w + (size_t)k0 * HDIM);
    float ah = 0.f, ac = 0.f;
    #pragma unroll 8
    for (int k = 0; k < HDIM / 4; ++k) {
      float4 w = wr[k];
      ah += w.x * s1h[4*k] + w.y * s1h[4*k+1] + w.z * s1h[4*k+2] + w.w * s1h[4*k+3];
      ac += w.x * s1c[4*k] + w.y * s1c[4*k+1] + w.z * s1c[4*k+2] + w.w * s1c[4*k+3];
    }
    const float bb = f2b[k0];
    rh = ah + bb * W1;
    rc = ac + bb * W1;
  }
  out[b * HDIM + tid] = rh;                      // agg(h_all) -> (1,B,256)
  out[BDIM * HDIM + b * HDIM + tid] = rc;        // agg(c_all)
}

extern "C" void kernel_launch(void* const* d_in, const int* in_sizes, int n_in,
                              void* d_out, int out_size, void* d_ws, size_t ws_size,
                              hipStream_t stream) {
  const float* x   = (const float*)d_in[0];
  const float* h0  = (const float*)d_in[1];
  const float* c0  = (const float*)d_in[2];
  const float* Wih = (const float*)d_in[3];
  const float* Whh = (const float*)d_in[4];
  const float* bih = (const float*)d_in[5];
  const float* bhh = (const float*)d_in[6];
  const float* f1w = (const float*)d_in[7];
  const float* f1b = (const float*)d_in[8];
  const float* f2w = (const float*)d_in[9];
  const float* f2b = (const float*)d_in[10];
  const int*  longp = (const int*)d_in[11];
  float* out  = (float*)d_out;
  float* sbuf = (float*)d_ws;   // 4 * B * H floats = 512 KB

  dim3 g1(BDIM, 4);
  fused_lstm<<<g1, 1024, 0, stream>>>(x, h0, c0, Wih, Whh, bih, bhh, longp, sbuf);
  out_kernel<<<BDIM, 256, 0, stream>>>(x, f1w, f1b, f2w, f2b, longp, sbuf, out);
}

// Round 3
// 168.903 us; speedup vs baseline: 1.0025x; 1.0025x over previous
//
#include <hip/hip_runtime.h>

#define BDIM 128
#define TDIM 512
#define DDIM 64
#define HDIM 256
#define TCHUNK 128                    // timesteps per block (blockIdx.z)
#define NTG   (TDIM / TCHUNK)         // 4
#define HH_FLOATS (BDIM * 4 * HDIM)   // 131072 floats = 512 KB

typedef short s16x8 __attribute__((ext_vector_type(8)));
typedef float f32x4 __attribute__((ext_vector_type(4)));

__device__ __forceinline__ short f2bf(float f) {
  __bf16 b = (__bf16)f;
  return __builtin_bit_cast(short, b);
}

__device__ __forceinline__ s16x8 pack_bf8(float4 lo, float4 hi) {
  s16x8 v;
  v[0] = f2bf(lo.x); v[1] = f2bf(lo.y); v[2] = f2bf(lo.z); v[3] = f2bf(lo.w);
  v[4] = f2bf(hi.x); v[5] = f2bf(hi.y); v[6] = f2bf(hi.z); v[7] = f2bf(hi.w);
  return v;
}

__device__ __forceinline__ float rcpf(float x) { return __builtin_amdgcn_rcpf(x); }
__device__ __forceinline__ float sigm(float x) { return rcpf(1.0f + __expf(-x)); }
__device__ __forceinline__ float tanh_fast(float x) { return 1.0f - 2.0f * rcpf(__expf(2.0f * x) + 1.0f); }

// hh[b][colw] = Whh[colw]·h0[b] + bih[colw] + bhh[colw]
// Grid (128, 4), 256 threads: block = (b, quarter of the 1024 gate-cols).
__global__ __launch_bounds__(256) void hh_kernel(
    const float* __restrict__ h0, const float* __restrict__ Whh,
    const float* __restrict__ bih, const float* __restrict__ bhh,
    float* __restrict__ hh)
{
  const int b = blockIdx.x, c = blockIdx.y, tid = threadIdx.x;
  __shared__ float hs[HDIM];
  hs[tid] = h0[b * HDIM + tid];
  __syncthreads();

  const int colw = c * 256 + tid;
  const float4* wr = (const float4*)(Whh + (size_t)colw * HDIM);
  const float4* hv = (const float4*)hs;
  float acc = 0.f;
  #pragma unroll 8
  for (int k = 0; k < HDIM / 4; ++k) {
    float4 w = wr[k], h4 = hv[k];
    acc += w.x * h4.x + w.y * h4.y + w.z * h4.z + w.w * h4.w;
  }
  hh[(size_t)b * 1024 + colw] = acc + bih[colw] + bhh[colw];
}

// Grid: (128, 4, 4) blocks, 256 threads (4 waves). Block = (b, h-chunk, t-chunk).
// Wave w owns h columns [hc*64 + w*16, +16) for timesteps [tg*128, +128).
__global__ __launch_bounds__(256, 8) void fused_lstm(
    const float* __restrict__ x, const float* __restrict__ c0,
    const float* __restrict__ Wih, const float* __restrict__ hh,
    const int* __restrict__ longp, float* __restrict__ sbuf)
{
  const int b    = blockIdx.x;
  const int hc   = blockIdx.y;          // 0..3
  const int tg   = blockIdx.z;          // 0..3
  const int tid  = threadIdx.x;
  const int wave = tid >> 6;            // 0..3 (h-slice)
  const int lane = tid & 63;
  const int col  = lane & 15;
  const int kg   = lane >> 4;           // 0..3
  const int h    = hc * 64 + wave * 16 + col;

  __shared__ float w0s[TCHUNK];
  __shared__ float w1s[TCHUNK];

  const float* xb = x + (size_t)b * (TDIM * DDIM);
  const int t0 = tg * TCHUNK;
  const float inv_long = 1.0f / (float)(*longp);

  if (tid < TCHUNK) {
    const int tt = t0 + tid;
    w0s[tid] = (tt == 0) ? 0.f : xb[tt * DDIM + 0] * inv_long;  // t=0 mask
    w1s[tid] = (tt == 0) ? 0.f : xb[tt * DDIM + 1];
  }
  __syncthreads();

  float hhv[4];
  #pragma unroll
  for (int g = 0; g < 4; ++g) hhv[g] = hh[(size_t)b * 1024 + g * HDIM + h];
  const float cprev = c0[b * HDIM + h];

  // W_ih fragments: B[k][n] = W_ih[n][k]; contiguous 8-float read per lane.
  s16x8 wf[4][2];
  #pragma unroll
  for (int g = 0; g < 4; ++g) {
    const float4* wrow = (const float4*)(Wih + (size_t)(g * HDIM + h) * DDIM);
    #pragma unroll
    for (int ks = 0; ks < 2; ++ks)
      wf[g][ks] = pack_bf8(wrow[kg * 2 + ks * 8], wrow[kg * 2 + ks * 8 + 1]);
  }

  float s0h = 0.f, s1h = 0.f, s0c = 0.f, s1c = 0.f;

  // A fragment: row = t0 + tb + (lane&15), k = kg*8 + j (+32)
  const float* arow = xb + (size_t)(t0 + col) * DDIM + kg * 8;

  float4 cur0 = *(const float4*)(arow + 0);
  float4 cur1 = *(const float4*)(arow + 4);
  float4 cur2 = *(const float4*)(arow + 32);
  float4 cur3 = *(const float4*)(arow + 36);
  float4 nxt0 = cur0, nxt1 = cur1, nxt2 = cur2, nxt3 = cur3;

  for (int tb = 0; tb < TCHUNK; tb += 16) {
    if (tb + 16 < TCHUNK) {
      const float* p = arow + (size_t)(tb + 16) * DDIM;
      nxt0 = *(const float4*)(p + 0);
      nxt1 = *(const float4*)(p + 4);
      nxt2 = *(const float4*)(p + 32);
      nxt3 = *(const float4*)(p + 36);
    }
    s16x8 a0 = pack_bf8(cur0, cur1);
    s16x8 a1 = pack_bf8(cur2, cur3);

    f32x4 acc[4];
    #pragma unroll
    for (int g = 0; g < 4; ++g) {
      f32x4 z = {hhv[g], hhv[g], hhv[g], hhv[g]};   // bias+hh folded into C
      z = __builtin_amdgcn_mfma_f32_16x16x32_bf16(a0, wf[g][0], z, 0, 0, 0);
      z = __builtin_amdgcn_mfma_f32_16x16x32_bf16(a1, wf[g][1], z, 0, 0, 0);
      acc[g] = z;
    }

    #pragma unroll
    for (int r = 0; r < 4; ++r) {
      const int lt = tb + kg * 4 + r;        // C/D row = kg*4+r, col = lane&15
      float ig = sigm(acc[0][r]);
      float fg = sigm(acc[1][r]);
      float gg = tanh_fast(acc[2][r]);
      float og = sigm(acc[3][r]);
      float cc = fg * cprev + ig * gg;
      float hv = og * tanh_fast(cc);
      float a0w = w0s[lt], a1w = w1s[lt];    // w*[t=0]==0 handles the mask
      s0h += hv * a0w; s1h += hv * a1w;
      s0c += cc * a0w; s1c += cc * a1w;
    }
    cur0 = nxt0; cur1 = nxt1; cur2 = nxt2; cur3 = nxt3;
  }

  // reduce over the 4 k-groups (lanes sharing col)
  s0h += __shfl_xor(s0h, 16, 64); s0h += __shfl_xor(s0h, 32, 64);
  s1h += __shfl_xor(s1h, 16, 64); s1h += __shfl_xor(s1h, 32, 64);
  s0c += __shfl_xor(s0c, 16, 64); s0c += __shfl_xor(s0c, 32, 64);
  s1c += __shfl_xor(s1c, 16, 64); s1c += __shfl_xor(s1c, 32, 64);

  if (kg == 0) {
    float* P = sbuf + HH_FLOATS;
    const size_t idx = (size_t)b * HDIM + h;
    P[((size_t)(tg * 4 + 0) * BDIM * HDIM) + idx] = s0h;
    P[((size_t)(tg * 4 + 1) * BDIM * HDIM) + idx] = s1h;
    P[((size_t)(tg * 4 + 2) * BDIM * HDIM) + idx] = s0c;
    P[((size_t)(tg * 4 + 3) * BDIM * HDIM) + idx] = s1c;
  }
}

// Grid: 128 blocks (b), 256 threads. Sums tg partials + GEMV epilogue.
__global__ __launch_bounds__(256) void out_kernel(
    const float* __restrict__ x, const float* __restrict__ f1w,
    const float* __restrict__ f1b, const float* __restrict__ f2w,
    const float* __restrict__ f2b, const int* __restrict__ longp,
    const float* __restrict__ sbuf, float* __restrict__ out)
{
  const int b = blockIdx.x, tid = threadIdx.x;
  __shared__ float s0h[256], s1h[256], s0c[256], s1c[256];
  __shared__ float wsum[8];
  const float* xb = x + (size_t)b * (TDIM * DDIM);
  const float* P  = sbuf + HH_FLOATS;
  const size_t idx = (size_t)b * HDIM + tid;

  float v0 = 0.f, v1 = 0.f, v2 = 0.f, v3 = 0.f;
  #pragma unroll
  for (int tg = 0; tg < NTG; ++tg) {
    v0 += P[((size_t)(tg * 4 + 0) * BDIM * HDIM) + idx];
    v1 += P[((size_t)(tg * 4 + 1) * BDIM * HDIM) + idx];
    v2 += P[((size_t)(tg * 4 + 2) * BDIM * HDIM) + idx];
    v3 += P[((size_t)(tg * 4 + 3) * BDIM * HDIM) + idx];
  }
  s0h[tid] = v0; s1h[tid] = v1; s0c[tid] = v2; s1c[tid] = v3;

  float w0p = 0.f, w1p = 0.f;
  for (int t = tid; t < TDIM; t += 256) {
    w0p += xb[t * DDIM];
    w1p += xb[t * DDIM + 1];
  }
  #pragma unroll
  for (int off = 1; off < 64; off <<= 1) {
    w0p += __shfl_xor(w0p, off, 64);
    w1p += __shfl_xor(w1p, off, 64);
  }
  if ((tid & 63) == 0) { wsum[tid >> 6] = w0p; wsum[4 + (tid >> 6)] = w1p; }
  __syncthreads();

  const float inv_long = 1.0f / (float)(*longp);
  const float W0 = (wsum[0] + wsum[1] + wsum[2] + wsum[3]) * inv_long; // all t
  const float W1 = (wsum[4] + wsum[5] + wsum[6] + wsum[7]);

  float rh, rc;
  if (tid < 128) {                       // "first": f1_w with w0-weighted sums
    const float4* wr = (const float4*)(f1w + (size_t)tid * HDIM);
    float ah = 0.f, ac = 0.f;
    #pragma unroll 8
    for (int k = 0; k < HDIM / 4; ++k) {
      float4 w = wr[k];
      ah += w.x * s0h[4*k] + w.y * s0h[4*k+1] + w.z * s0h[4*k+2] + w.w * s0h[4*k+3];
      ac += w.x * s0c[4*k] + w.y * s0c[4*k+1] + w.z * s0c[4*k+2] + w.w * s0c[4*k+3];
    }
    const float bb = f1b[tid];
    rh = ah + bb * W0;
    rc = ac + bb * W0;
  } else {                               // "second": f2_w with w1-weighted sums
    const int k0 = tid - 128;
    const float4* wr = (const float4*)(f2w + (size_t)k0 * HDIM);
    float ah = 0.f, ac = 0.f;
    #pragma unroll 8
    for (int k = 0; k < HDIM / 4; ++k) {
      float4 w = wr[k];
      ah += w.x * s1h[4*k] + w.y * s1h[4*k+1] + w.z * s1h[4*k+2] + w.w * s1h[4*k+3];
      ac += w.x * s1c[4*k] + w.y * s1c[4*k+1] + w.z * s1c[4*k+2] + w.w * s1c[4*k+3];
    }
    const float bb = f2b[k0];
    rh = ah + bb * W1;
    rc = ac + bb * W1;
  }
  out[b * HDIM + tid] = rh;                      // agg(h_all) -> (1,B,256)
  out[BDIM * HDIM + b * HDIM + tid] = rc;        // agg(c_all)
}

extern "C" void kernel_launch(void* const* d_in, const int* in_sizes, int n_in,
                              void* d_out, int out_size, void* d_ws, size_t ws_size,
                              hipStream_t stream) {
  const float* x   = (const float*)d_in[0];
  const float* h0  = (const float*)d_in[1];
  const float* c0  = (const float*)d_in[2];
  const float* Wih = (const float*)d_in[3];
  const float* Whh = (const float*)d_in[4];
  const float* bih = (const float*)d_in[5];
  const float* bhh = (const float*)d_in[6];
  const float* f1w = (const float*)d_in[7];
  const float* f1b = (const float*)d_in[8];
  const float* f2w = (const float*)d_in[9];
  const float* f2b = (const float*)d_in[10];
  const int*  longp = (const int*)d_in[11];
  float* out  = (float*)d_out;
  float* sbuf = (float*)d_ws;   // hh (512 KB) + partials (2 MB) = 2.5 MB

  dim3 gh(BDIM, 4);
  hh_kernel<<<gh, 256, 0, stream>>>(h0, Whh, bih, bhh, sbuf);
  dim3 g1(BDIM, 4, NTG);
  fused_lstm<<<g1, 256, 0, stream>>>(x, c0, Wih, sbuf, longp, sbuf);
  out_kernel<<<BDIM, 256, 0, stream>>>(x, f1w, f1b, f2w, f2b, longp, sbuf, out);
}

// Round 4
// 79.671 us; speedup vs baseline: 2.1253x; 2.1200x over previous
//
#include <hip/hip_runtime.h>

#define BDIM 128
#define TDIM 512
#define DDIM 64
#define HDIM 256
#define TCHUNK 128                    // timesteps per block (blockIdx.z)
#define NTG   (TDIM / TCHUNK)         // 4
#define HH_FLOATS (BDIM * 4 * HDIM)   // 131072 floats = 512 KB

typedef short s16x8 __attribute__((ext_vector_type(8)));
typedef float f32x4 __attribute__((ext_vector_type(4)));

__device__ __forceinline__ short f2bf(float f) {
  __bf16 b = (__bf16)f;
  return __builtin_bit_cast(short, b);
}

__device__ __forceinline__ s16x8 pack_bf8(float4 lo, float4 hi) {
  s16x8 v;
  v[0] = f2bf(lo.x); v[1] = f2bf(lo.y); v[2] = f2bf(lo.z); v[3] = f2bf(lo.w);
  v[4] = f2bf(hi.x); v[5] = f2bf(hi.y); v[6] = f2bf(hi.z); v[7] = f2bf(hi.w);
  return v;
}

__device__ __forceinline__ float rcpf(float x) { return __builtin_amdgcn_rcpf(x); }
__device__ __forceinline__ float sigm(float x) { return rcpf(1.0f + __expf(-x)); }
__device__ __forceinline__ float tanh_fast(float x) { return 1.0f - 2.0f * rcpf(__expf(2.0f * x) + 1.0f); }

// hh[b][colw] = Whh[colw]·h0[b] + bih[colw] + bhh[colw]
// Grid (128, 4), 256 threads: block = (b, quarter of the 1024 gate-cols).
__global__ __launch_bounds__(256) void hh_kernel(
    const float* __restrict__ h0, const float* __restrict__ Whh,
    const float* __restrict__ bih, const float* __restrict__ bhh,
    float* __restrict__ hh)
{
  const int b = blockIdx.x, c = blockIdx.y, tid = threadIdx.x;
  __shared__ float hs[HDIM];
  hs[tid] = h0[b * HDIM + tid];
  __syncthreads();

  const int colw = c * 256 + tid;
  const float4* wr = (const float4*)(Whh + (size_t)colw * HDIM);
  const float4* hv = (const float4*)hs;
  float acc = 0.f;
  #pragma unroll 8
  for (int k = 0; k < HDIM / 4; ++k) {
    float4 w = wr[k], h4 = hv[k];
    acc += w.x * h4.x + w.y * h4.y + w.z * h4.z + w.w * h4.w;
  }
  hh[(size_t)b * 1024 + colw] = acc + bih[colw] + bhh[colw];
}

// Grid: (128, 4, 4) blocks, 256 threads (4 waves). Block = (b, h-chunk, t-chunk).
// Wave w owns h columns [hc*64 + w*16, +16) for timesteps [tg*128, +128).
// launch_bounds min-waves=4: 128-VGPR budget — rounds 2/3 showed that forcing
// 8 waves/SIMD (64-reg cap) spills ~560 MB to scratch and is 2x SLOWER.
__global__ __launch_bounds__(256, 4) void fused_lstm(
    const float* __restrict__ x, const float* __restrict__ c0,
    const float* __restrict__ Wih, const float* __restrict__ hh,
    const int* __restrict__ longp, float* __restrict__ sbuf)
{
  const int b    = blockIdx.x;
  const int hc   = blockIdx.y;          // 0..3
  const int tg   = blockIdx.z;          // 0..3
  const int tid  = threadIdx.x;
  const int wave = tid >> 6;            // 0..3 (h-slice)
  const int lane = tid & 63;
  const int col  = lane & 15;
  const int kg   = lane >> 4;           // 0..3
  const int h    = hc * 64 + wave * 16 + col;

  __shared__ float w0s[TCHUNK];
  __shared__ float w1s[TCHUNK];

  const float* xb = x + (size_t)b * (TDIM * DDIM);
  const int t0 = tg * TCHUNK;
  const float inv_long = 1.0f / (float)(*longp);

  if (tid < TCHUNK) {
    const int tt = t0 + tid;
    w0s[tid] = (tt == 0) ? 0.f : xb[tt * DDIM + 0] * inv_long;  // t=0 mask
    w1s[tid] = (tt == 0) ? 0.f : xb[tt * DDIM + 1];
  }
  __syncthreads();

  float hhv[4];
  #pragma unroll
  for (int g = 0; g < 4; ++g) hhv[g] = hh[(size_t)b * 1024 + g * HDIM + h];
  const float cprev = c0[b * HDIM + h];

  // W_ih fragments: B[k][n] = W_ih[n][k]; contiguous 8-float read per lane.
  s16x8 wf[4][2];
  #pragma unroll
  for (int g = 0; g < 4; ++g) {
    const float4* wrow = (const float4*)(Wih + (size_t)(g * HDIM + h) * DDIM);
    #pragma unroll
    for (int ks = 0; ks < 2; ++ks)
      wf[g][ks] = pack_bf8(wrow[kg * 2 + ks * 8], wrow[kg * 2 + ks * 8 + 1]);
  }

  float s0h = 0.f, s1h = 0.f, s0c = 0.f, s1c = 0.f;

  // A fragment: row = t0 + tb + (lane&15), k = kg*8 + j (+32)
  const float* arow = xb + (size_t)(t0 + col) * DDIM + kg * 8;

  // keep CURRENT tile packed (8 regs); only the in-flight prefetch is raw f32
  float4 nxt0 = *(const float4*)(arow + 0);
  float4 nxt1 = *(const float4*)(arow + 4);
  float4 nxt2 = *(const float4*)(arow + 32);
  float4 nxt3 = *(const float4*)(arow + 36);
  s16x8 a0 = pack_bf8(nxt0, nxt1);
  s16x8 a1 = pack_bf8(nxt2, nxt3);

  for (int tb = 0; tb < TCHUNK; tb += 16) {
    const bool has_next = (tb + 16) < TCHUNK;
    if (has_next) {
      const float* p = arow + (size_t)(tb + 16) * DDIM;
      nxt0 = *(const float4*)(p + 0);
      nxt1 = *(const float4*)(p + 4);
      nxt2 = *(const float4*)(p + 32);
      nxt3 = *(const float4*)(p + 36);
    }

    f32x4 acc[4];
    #pragma unroll
    for (int g = 0; g < 4; ++g) {
      f32x4 z = {hhv[g], hhv[g], hhv[g], hhv[g]};   // bias+hh folded into C
      z = __builtin_amdgcn_mfma_f32_16x16x32_bf16(a0, wf[g][0], z, 0, 0, 0);
      z = __builtin_amdgcn_mfma_f32_16x16x32_bf16(a1, wf[g][1], z, 0, 0, 0);
      acc[g] = z;
    }

    #pragma unroll
    for (int r = 0; r < 4; ++r) {
      const int lt = tb + kg * 4 + r;        // C/D row = kg*4+r, col = lane&15
      float ig = sigm(acc[0][r]);
      float fg = sigm(acc[1][r]);
      float gg = tanh_fast(acc[2][r]);
      float og = sigm(acc[3][r]);
      float cc = fg * cprev + ig * gg;
      float hv = og * tanh_fast(cc);
      float a0w = w0s[lt], a1w = w1s[lt];    // w*[t=0]==0 handles the mask
      s0h += hv * a0w; s1h += hv * a1w;
      s0c += cc * a0w; s1c += cc * a1w;
    }

    if (has_next) {
      a0 = pack_bf8(nxt0, nxt1);
      a1 = pack_bf8(nxt2, nxt3);
    }
  }

  // reduce over the 4 k-groups (lanes sharing col)
  s0h += __shfl_xor(s0h, 16, 64); s0h += __shfl_xor(s0h, 32, 64);
  s1h += __shfl_xor(s1h, 16, 64); s1h += __shfl_xor(s1h, 32, 64);
  s0c += __shfl_xor(s0c, 16, 64); s0c += __shfl_xor(s0c, 32, 64);
  s1c += __shfl_xor(s1c, 16, 64); s1c += __shfl_xor(s1c, 32, 64);

  if (kg == 0) {
    float* P = sbuf + HH_FLOATS;
    const size_t idx = (size_t)b * HDIM + h;
    P[((size_t)(tg * 4 + 0) * BDIM * HDIM) + idx] = s0h;
    P[((size_t)(tg * 4 + 1) * BDIM * HDIM) + idx] = s1h;
    P[((size_t)(tg * 4 + 2) * BDIM * HDIM) + idx] = s0c;
    P[((size_t)(tg * 4 + 3) * BDIM * HDIM) + idx] = s1c;
  }
}

// Grid: 128 blocks (b), 256 threads. Sums tg partials + GEMV epilogue.
__global__ __launch_bounds__(256) void out_kernel(
    const float* __restrict__ x, const float* __restrict__ f1w,
    const float* __restrict__ f1b, const float* __restrict__ f2w,
    const float* __restrict__ f2b, const int* __restrict__ longp,
    const float* __restrict__ sbuf, float* __restrict__ out)
{
  const int b = blockIdx.x, tid = threadIdx.x;
  __shared__ float s0h[256], s1h[256], s0c[256], s1c[256];
  __shared__ float wsum[8];
  const float* xb = x + (size_t)b * (TDIM * DDIM);
  const float* P  = sbuf + HH_FLOATS;
  const size_t idx = (size_t)b * HDIM + tid;

  float v0 = 0.f, v1 = 0.f, v2 = 0.f, v3 = 0.f;
  #pragma unroll
  for (int tg = 0; tg < NTG; ++tg) {
    v0 += P[((size_t)(tg * 4 + 0) * BDIM * HDIM) + idx];
    v1 += P[((size_t)(tg * 4 + 1) * BDIM * HDIM) + idx];
    v2 += P[((size_t)(tg * 4 + 2) * BDIM * HDIM) + idx];
    v3 += P[((size_t)(tg * 4 + 3) * BDIM * HDIM) + idx];
  }
  s0h[tid] = v0; s1h[tid] = v1; s0c[tid] = v2; s1c[tid] = v3;

  float w0p = 0.f, w1p = 0.f;
  for (int t = tid; t < TDIM; t += 256) {
    w0p += xb[t * DDIM];
    w1p += xb[t * DDIM + 1];
  }
  #pragma unroll
  for (int off = 1; off < 64; off <<= 1) {
    w0p += __shfl_xor(w0p, off, 64);
    w1p += __shfl_xor(w1p, off, 64);
  }
  if ((tid & 63) == 0) { wsum[tid >> 6] = w0p; wsum[4 + (tid >> 6)] = w1p; }
  __syncthreads();

  const float inv_long = 1.0f / (float)(*longp);
  const float W0 = (wsum[0] + wsum[1] + wsum[2] + wsum[3]) * inv_long; // all t
  const float W1 = (wsum[4] + wsum[5] + wsum[6] + wsum[7]);

  float rh, rc;
  if (tid < 128) {                       // "first": f1_w with w0-weighted sums
    const float4* wr = (const float4*)(f1w + (size_t)tid * HDIM);
    float ah = 0.f, ac = 0.f;
    #pragma unroll 8
    for (int k = 0; k < HDIM / 4; ++k) {
      float4 w = wr[k];
      ah += w.x * s0h[4*k] + w.y * s0h[4*k+1] + w.z * s0h[4*k+2] + w.w * s0h[4*k+3];
      ac += w.x * s0c[4*k] + w.y * s0c[4*k+1] + w.z * s0c[4*k+2] + w.w * s0c[4*k+3];
    }
    const float bb = f1b[tid];
    rh = ah + bb * W0;
    rc = ac + bb * W0;
  } else {                               // "second": f2_w with w1-weighted sums
    const int k0 = tid - 128;
    const float4* wr = (const float4*)(f2w + (size_t)k0 * HDIM);
    float ah = 0.f, ac = 0.f;
    #pragma unroll 8
    for (int k = 0; k < HDIM / 4; ++k) {
      float4 w = wr[k];
      ah += w.x * s1h[4*k] + w.y * s1h[4*k+1] + w.z * s1h[4*k+2] + w.w * s1h[4*k+3];
      ac += w.x * s1c[4*k] + w.y * s1c[4*k+1] + w.z * s1c[4*k+2] + w.w * s1c[4*k+3];
    }
    const float bb = f2b[k0];
    rh = ah + bb * W1;
    rc = ac + bb * W1;
  }
  out[b * HDIM + tid] = rh;                      // agg(h_all) -> (1,B,256)
  out[BDIM * HDIM + b * HDIM + tid] = rc;        // agg(c_all)
}

extern "C" void kernel_launch(void* const* d_in, const int* in_sizes, int n_in,
                              void* d_out, int out_size, void* d_ws, size_t ws_size,
                              hipStream_t stream) {
  const float* x   = (const float*)d_in[0];
  const float* h0  = (const float*)d_in[1];
  const float* c0  = (const float*)d_in[2];
  const float* Wih = (const float*)d_in[3];
  const float* Whh = (const float*)d_in[4];
  const float* bih = (const float*)d_in[5];
  const float* bhh = (const float*)d_in[6];
  const float* f1w = (const float*)d_in[7];
  const float* f1b = (const float*)d_in[8];
  const float* f2w = (const float*)d_in[9];
  const float* f2b = (const float*)d_in[10];
  const int*  longp = (const int*)d_in[11];
  float* out  = (float*)d_out;
  float* sbuf = (float*)d_ws;   // hh (512 KB) + partials (2 MB) = 2.5 MB

  dim3 gh(BDIM, 4);
  hh_kernel<<<gh, 256, 0, stream>>>(h0, Whh, bih, bhh, sbuf);
  dim3 g1(BDIM, 4, NTG);
  fused_lstm<<<g1, 256, 0, stream>>>(x, c0, Wih, sbuf, longp, sbuf);
  out_kernel<<<BDIM, 256, 0, stream>>>(x, f1w, f1b, f2w, f2b, longp, sbuf, out);
}